// Round 1
// baseline (3963.475 us; speedup 1.0000x reference)
//
#include <hip/hip_runtime.h>

#define TT 512
#define BB 1024
#define FF 32
#define HH 64
#define GG 256   // 4*H gates per direction

// Static device scratch (ws_size-independent). Fully overwritten every call.
__device__ float g_h1[(size_t)TT * BB * 2 * HH];   // [T][B][128] layer-1 input
__device__ float g_pre0[(size_t)2 * TT * BB * GG]; // [dir][T][B][256] layer-0 pre-gates
__device__ float g_pre1[(size_t)TT * BB * GG];     // [T][B][256] layer-1 fwd pre-gates
__device__ float g_hf[(size_t)BB * HH];            // [B][64] final fwd h of layer1

__device__ __forceinline__ float fsigm(float x) {
    float e = __builtin_amdgcn_exp2f(x * -1.44269504088896f);
    return __builtin_amdgcn_rcpf(1.0f + e);
}
__device__ __forceinline__ float ftanh(float x) {
    float e = __builtin_amdgcn_exp2f(x * -2.88539008177793f);
    return 2.0f * __builtin_amdgcn_rcpf(1.0f + e) - 1.0f;
}
// Wave-uniform broadcast via v_readlane (VALU->SGPR, zero LDS-pipe cost).
__device__ __forceinline__ float rlane(float v, int l) {
    return __int_as_float(__builtin_amdgcn_readlane(__float_as_int(v), l));
}

// ---------------------------------------------------------------------------
// Layer-0 input pre-gates (unchanged).
// ---------------------------------------------------------------------------
__global__ __launch_bounds__(256, 4) void pre_gemm0(
    const float* __restrict__ x,      // [B][T][F]
    const float* __restrict__ w_ih,   // [2][G][F]
    const float* __restrict__ b_ih,
    const float* __restrict__ b_hh)
{
    const int tid = threadIdx.x;          // gate
    const int b   = blockIdx.x >> 1;
    const int dir = blockIdx.x & 1;

    __shared__ __align__(16) float4 w4[8 * 256];    // [kq][gate], 32 KB
    __shared__ __align__(16) float xbuf[2][256];    // 8 t-rows x 32 f, dbuf

    const float4* wsrc = (const float4*)(w_ih + ((size_t)dir * GG + tid) * FF);
#pragma unroll
    for (int kq = 0; kq < 8; ++kq) w4[kq * 256 + tid] = wsrc[kq];
    const float bias = b_ih[dir * GG + tid] + b_hh[dir * GG + tid];

    const float* xbase = x + (size_t)b * TT * FF;
    xbuf[0][tid] = xbase[tid];            // tile 0 (rows 0..7), coalesced
    const size_t OS = (size_t)BB * GG;

    for (int tc = 0; tc < 64; ++tc) {
        const int cur = tc & 1;
        __syncthreads();   // xbuf[cur] ready; prev reads of xbuf[1-cur] done

        float vnext = 0.f;
        if (tc + 1 < 64) vnext = xbase[(tc + 1) * 256 + tid];   // coalesced

        float a0 = bias, a1 = bias, a2 = bias, a3 = bias,
              a4 = bias, a5 = bias, a6 = bias, a7 = bias;
#pragma unroll
        for (int kq = 0; kq < 8; ++kq) {
            float4 wq = w4[kq * 256 + tid];
            const float4* xr = (const float4*)xbuf[cur];
            float4 q;
            q = xr[0 * 8 + kq]; a0 += q.x*wq.x + q.y*wq.y + q.z*wq.z + q.w*wq.w;
            q = xr[1 * 8 + kq]; a1 += q.x*wq.x + q.y*wq.y + q.z*wq.z + q.w*wq.w;
            q = xr[2 * 8 + kq]; a2 += q.x*wq.x + q.y*wq.y + q.z*wq.z + q.w*wq.w;
            q = xr[3 * 8 + kq]; a3 += q.x*wq.x + q.y*wq.y + q.z*wq.z + q.w*wq.w;
            q = xr[4 * 8 + kq]; a4 += q.x*wq.x + q.y*wq.y + q.z*wq.z + q.w*wq.w;
            q = xr[5 * 8 + kq]; a5 += q.x*wq.x + q.y*wq.y + q.z*wq.z + q.w*wq.w;
            q = xr[6 * 8 + kq]; a6 += q.x*wq.x + q.y*wq.y + q.z*wq.z + q.w*wq.w;
            q = xr[7 * 8 + kq]; a7 += q.x*wq.x + q.y*wq.y + q.z*wq.z + q.w*wq.w;
        }
        float* op = g_pre0 + (((size_t)dir * TT + tc * 8) * BB + b) * GG + tid;
        op[0] = a0; op[1 * OS] = a1; op[2 * OS] = a2; op[3 * OS] = a3;
        op[4 * OS] = a4; op[5 * OS] = a5; op[6 * OS] = a6; op[7 * OS] = a7;

        if (tc + 1 < 64) xbuf[1 - cur][tid] = vnext;
    }
}

// ---------------------------------------------------------------------------
// Wave-per-(batch,dir) recurrent scan. Lane l owns cell l and gates
// {l, 64+l, 128+l, 192+l}: cell update is thread-local, h broadcast is one
// v_readlane feeding 4 FMAs, NO barriers and NO LDS exchange in the T loop.
// Weight rows i/f/g in VGPRs (48 float4 = 192 VGPR); o-row in LDS with a
// 17-float4 padded row stride (bank-quad = (l+q)&7 -> conflict-free b128).
// L=0: layer0 both dirs (grid 512 = 2 dir x 128 x 4-batch blocks).
// L=1: layer1 fwd only (grid 256 x 4-batch blocks), stores only final h.
// ---------------------------------------------------------------------------
template <int L>
__global__ __launch_bounds__(256, 2) void lstm_scan(
    const float* __restrict__ w_hh)   // [2][G][64]
{
    const int tid = threadIdx.x;
    const int l   = tid & 63;
    const int wv  = tid >> 6;
    const int dir = (L == 0) ? (blockIdx.x & 1) : 0;
    const int b   = ((L == 0) ? (int)(blockIdx.x >> 1) : (int)blockIdx.x) * 4 + wv;

    // o-gate rows (192..255), padded to 17 float4/row: 17.4 KB
    __shared__ __align__(16) float4 wo_lds[64 * 17];

    const float* wbase = w_hh + (size_t)dir * GG * HH;
    for (int idx = tid; idx < 64 * 16; idx += 256) {
        const int r = idx >> 4, q = idx & 15;
        wo_lds[r * 17 + q] = ((const float4*)(wbase + (size_t)(192 + r) * HH))[q];
    }

    // Per-lane register weight rows: i(l), f(64+l), g(128+l).
    float4 wi[16], wf[16], wg[16];
    {
        const float4* pi_ = (const float4*)(wbase + (size_t)(0   + l) * HH);
        const float4* pf_ = (const float4*)(wbase + (size_t)(64  + l) * HH);
        const float4* pg_ = (const float4*)(wbase + (size_t)(128 + l) * HH);
#pragma unroll
        for (int q = 0; q < 16; ++q) { wi[q] = pi_[q]; wf[q] = pf_[q]; wg[q] = pg_[q]; }
    }
    __syncthreads();   // wo_lds ready (only barrier in the kernel)

    const float* pre = (L == 0) ? (g_pre0 + (size_t)dir * TT * BB * GG) : g_pre1;
    const float4* wol = wo_lds + l * 17;

    float c = 0.f, h = 0.f;
    const int t0 = dir ? (TT - 1) : 0;
    const float* pp = pre + ((size_t)t0 * BB + b) * GG;
    float pi = pp[l], pf = pp[64 + l], pg = pp[128 + l], po = pp[192 + l];

    for (int s = 0; s < TT; ++s) {
        const int t = dir ? (TT - 1 - s) : s;

        // Prefetch next step's pre-gates (coalesced 256B per 64-gate chunk).
        float ni = 0.f, nf = 0.f, ng = 0.f, no = 0.f;
        if (s + 1 < TT) {
            const int tn = dir ? (TT - 2 - s) : (s + 1);
            const float* np = pre + ((size_t)tn * BB + b) * GG;
            ni = np[l]; nf = np[64 + l]; ng = np[128 + l]; no = np[192 + l];
        }

        float ai = pi, af = pf, ag = pg, ao = po;

#define STEPQ(q) do {                                                        \
        float4 wo = wol[q];                                                  \
        float s0 = rlane(h, 4*(q)+0), s1 = rlane(h, 4*(q)+1),                \
              s2 = rlane(h, 4*(q)+2), s3 = rlane(h, 4*(q)+3);                \
        ai += s0*wi[q].x + s1*wi[q].y + s2*wi[q].z + s3*wi[q].w;             \
        af += s0*wf[q].x + s1*wf[q].y + s2*wf[q].z + s3*wf[q].w;             \
        ag += s0*wg[q].x + s1*wg[q].y + s2*wg[q].z + s3*wg[q].w;             \
        ao += s0*wo.x    + s1*wo.y    + s2*wo.z    + s3*wo.w;                \
    } while (0)

        STEPQ(0);  STEPQ(1);  STEPQ(2);  STEPQ(3);
        STEPQ(4);  STEPQ(5);  STEPQ(6);  STEPQ(7);
        STEPQ(8);  STEPQ(9);  STEPQ(10); STEPQ(11);
        STEPQ(12); STEPQ(13); STEPQ(14); STEPQ(15);
#undef STEPQ

        const float ig = fsigm(ai);
        const float fg = fsigm(af);
        const float gg = ftanh(ag);
        const float og = fsigm(ao);
        c = fg * c + ig * gg;
        h = og * ftanh(c);

        if (L == 0) {
            g_h1[((size_t)t * BB + b) * (2 * HH) + dir * HH + l] = h;  // coalesced
        } else {
            if (s == TT - 1) g_hf[(size_t)b * HH + l] = h;
        }

        pi = ni; pf = nf; pg = ng; po = no;
    }
}

// ---------------------------------------------------------------------------
// Layer-1 forward input pre-gates (unchanged).
// ---------------------------------------------------------------------------
__global__ __launch_bounds__(256, 2) void pre_gemm1(
    const float* __restrict__ w_ih,   // [2][G][128] (dir 0 used)
    const float* __restrict__ b_ih,
    const float* __restrict__ b_hh)
{
    const int tid  = threadIdx.x;
    const int gl   = tid & 127;
    const int rg   = tid >> 7;
    const int b    = blockIdx.x >> 1;
    const int gate = (blockIdx.x & 1) * 128 + gl;

    __shared__ __align__(16) float4 w4[28 * 128];       // quads 0..27, 56 KB
    __shared__ __align__(16) float4 hstg[2][8 * 32];    // 8 t-rows x 32 q, dbuf 8 KB

    const float4* wsrc = (const float4*)w_ih + (size_t)gate * 32;
#pragma unroll
    for (int i = 0; i < 14; ++i) {
        int kq = rg * 14 + i;
        w4[kq * 128 + gl] = wsrc[kq];
    }
    float4 wr0 = wsrc[28], wr1 = wsrc[29], wr2 = wsrc[30], wr3 = wsrc[31];
    const float bias = b_ih[gate] + b_hh[gate];

    const int srow = tid >> 5, sq = tid & 31;
    hstg[0][srow * 32 + sq] =
        *((const float4*)(g_h1 + ((size_t)srow * BB + b) * 128) + sq);

    const size_t RS = (size_t)BB * GG;    // pre1 t-stride (floats)

    for (int tc = 0; tc < 64; ++tc) {
        const int cur = tc & 1;
        __syncthreads();   // hstg[cur] + w4 ready

        float4 vnext = make_float4(0.f, 0.f, 0.f, 0.f);
        if (tc + 1 < 64)
            vnext = *((const float4*)(g_h1 +
                      ((size_t)((tc + 1) * 8 + srow) * BB + b) * 128) + sq);

        const float4* hr0 = &hstg[cur][(rg * 4 + 0) * 32];
        const float4* hr1 = &hstg[cur][(rg * 4 + 1) * 32];
        const float4* hr2 = &hstg[cur][(rg * 4 + 2) * 32];
        const float4* hr3 = &hstg[cur][(rg * 4 + 3) * 32];

        float a0 = bias, a1 = bias, a2 = bias, a3 = bias;
#pragma unroll
        for (int kq = 0; kq < 28; ++kq) {
            float4 wq = w4[kq * 128 + gl];
            float4 q;
            q = hr0[kq]; a0 += q.x*wq.x + q.y*wq.y + q.z*wq.z + q.w*wq.w;
            q = hr1[kq]; a1 += q.x*wq.x + q.y*wq.y + q.z*wq.z + q.w*wq.w;
            q = hr2[kq]; a2 += q.x*wq.x + q.y*wq.y + q.z*wq.z + q.w*wq.w;
            q = hr3[kq]; a3 += q.x*wq.x + q.y*wq.y + q.z*wq.z + q.w*wq.w;
        }
        {
            float4 q;
            q = hr0[28]; a0 += q.x*wr0.x + q.y*wr0.y + q.z*wr0.z + q.w*wr0.w;
            q = hr1[28]; a1 += q.x*wr0.x + q.y*wr0.y + q.z*wr0.z + q.w*wr0.w;
            q = hr2[28]; a2 += q.x*wr0.x + q.y*wr0.y + q.z*wr0.z + q.w*wr0.w;
            q = hr3[28]; a3 += q.x*wr0.x + q.y*wr0.y + q.z*wr0.z + q.w*wr0.w;
            q = hr0[29]; a0 += q.x*wr1.x + q.y*wr1.y + q.z*wr1.z + q.w*wr1.w;
            q = hr1[29]; a1 += q.x*wr1.x + q.y*wr1.y + q.z*wr1.z + q.w*wr1.w;
            q = hr2[29]; a2 += q.x*wr1.x + q.y*wr1.y + q.z*wr1.z + q.w*wr1.w;
            q = hr3[29]; a3 += q.x*wr1.x + q.y*wr1.y + q.z*wr1.z + q.w*wr1.w;
            q = hr0[30]; a0 += q.x*wr2.x + q.y*wr2.y + q.z*wr2.z + q.w*wr2.w;
            q = hr1[30]; a1 += q.x*wr2.x + q.y*wr2.y + q.z*wr2.z + q.w*wr2.w;
            q = hr2[30]; a2 += q.x*wr2.x + q.y*wr2.y + q.z*wr2.z + q.w*wr2.w;
            q = hr3[30]; a3 += q.x*wr2.x + q.y*wr2.y + q.z*wr2.z + q.w*wr2.w;
            q = hr0[31]; a0 += q.x*wr3.x + q.y*wr3.y + q.z*wr3.z + q.w*wr3.w;
            q = hr1[31]; a1 += q.x*wr3.x + q.y*wr3.y + q.z*wr3.z + q.w*wr3.w;
            q = hr2[31]; a2 += q.x*wr3.x + q.y*wr3.y + q.z*wr3.z + q.w*wr3.w;
            q = hr3[31]; a3 += q.x*wr3.x + q.y*wr3.y + q.z*wr3.z + q.w*wr3.w;
        }
        {
            const int tb = tc * 8 + rg * 4;
            float* op = g_pre1 + ((size_t)tb * BB + b) * GG + gate;
            op[0 * RS] = a0; op[1 * RS] = a1; op[2 * RS] = a2; op[3 * RS] = a3;
        }
        if (tc + 1 < 64) hstg[1 - cur][srow * 32 + sq] = vnext;
    }
}

// ---------------------------------------------------------------------------
// Layer 1 backward single step (zero state on h1[T-1]) + FC head (unchanged).
// ---------------------------------------------------------------------------
#define FMAC4(W, P0, P1, P2, P3, K) do{                                   \
    float4 v_;                                                           \
    v_ = (P0)[K]; acc0 += W.x*v_.x; acc0 += W.y*v_.y; acc0 += W.z*v_.z; acc0 += W.w*v_.w; \
    v_ = (P1)[K]; acc1 += W.x*v_.x; acc1 += W.y*v_.y; acc1 += W.z*v_.z; acc1 += W.w*v_.w; \
    v_ = (P2)[K]; acc2 += W.x*v_.x; acc2 += W.y*v_.y; acc2 += W.z*v_.z; acc2 += W.w*v_.w; \
    v_ = (P3)[K]; acc3 += W.x*v_.x; acc3 += W.y*v_.y; acc3 += W.z*v_.z; acc3 += W.w*v_.w; \
}while(0)

__global__ __launch_bounds__(256, 2) void lstm_final(
    const float* __restrict__ w_ih,   // [2][G][128] (dir 1)
    const float* __restrict__ b_ih,
    const float* __restrict__ b_hh,
    const float* __restrict__ fc_w,   // [2][128]
    const float* __restrict__ fc_b,   // [2]
    float* __restrict__ out)          // [B][2]
{
    const int tid = threadIdx.x;
    const int b0  = blockIdx.x * 4;

    __shared__ __align__(16) float x_lds[4][128];
    __shared__ __align__(16) float gact[4][GG];
    __shared__ __align__(16) float last[4][128];

#pragma unroll
    for (int r = 0; r < 2; ++r) {
        int idx = tid + r * 256;
        int b = idx >> 7, col = idx & 127;
        x_lds[b][col] = g_h1[((size_t)(TT - 1) * BB + (b0 + b)) * 128 + col];
    }

    const float4* p = (const float4*)(w_ih + ((size_t)GG + tid) * 128);
    float4 w0 = p[0],  w1 = p[1],  w2 = p[2],  w3 = p[3],  w4 = p[4],  w5 = p[5],
           w6 = p[6],  w7 = p[7],  w8 = p[8],  w9 = p[9],  w10 = p[10], w11 = p[11],
           w12 = p[12], w13 = p[13], w14 = p[14], w15 = p[15], w16 = p[16], w17 = p[17],
           w18 = p[18], w19 = p[19], w20 = p[20], w21 = p[21], w22 = p[22], w23 = p[23],
           w24 = p[24], w25 = p[25], w26 = p[26], w27 = p[27], w28 = p[28], w29 = p[29],
           w30 = p[30], w31 = p[31];
    const float bias = b_ih[GG + tid] + b_hh[GG + tid];
    __syncthreads();

    const float4* xb0 = (const float4*)x_lds[0];
    const float4* xb1 = (const float4*)x_lds[1];
    const float4* xb2 = (const float4*)x_lds[2];
    const float4* xb3 = (const float4*)x_lds[3];

    float acc0 = bias, acc1 = bias, acc2 = bias, acc3 = bias;
    FMAC4(w0, xb0, xb1, xb2, xb3, 0);   FMAC4(w1, xb0, xb1, xb2, xb3, 1);
    FMAC4(w2, xb0, xb1, xb2, xb3, 2);   FMAC4(w3, xb0, xb1, xb2, xb3, 3);
    FMAC4(w4, xb0, xb1, xb2, xb3, 4);   FMAC4(w5, xb0, xb1, xb2, xb3, 5);
    FMAC4(w6, xb0, xb1, xb2, xb3, 6);   FMAC4(w7, xb0, xb1, xb2, xb3, 7);
    FMAC4(w8, xb0, xb1, xb2, xb3, 8);   FMAC4(w9, xb0, xb1, xb2, xb3, 9);
    FMAC4(w10, xb0, xb1, xb2, xb3, 10); FMAC4(w11, xb0, xb1, xb2, xb3, 11);
    FMAC4(w12, xb0, xb1, xb2, xb3, 12); FMAC4(w13, xb0, xb1, xb2, xb3, 13);
    FMAC4(w14, xb0, xb1, xb2, xb3, 14); FMAC4(w15, xb0, xb1, xb2, xb3, 15);
    FMAC4(w16, xb0, xb1, xb2, xb3, 16); FMAC4(w17, xb0, xb1, xb2, xb3, 17);
    FMAC4(w18, xb0, xb1, xb2, xb3, 18); FMAC4(w19, xb0, xb1, xb2, xb3, 19);
    FMAC4(w20, xb0, xb1, xb2, xb3, 20); FMAC4(w21, xb0, xb1, xb2, xb3, 21);
    FMAC4(w22, xb0, xb1, xb2, xb3, 22); FMAC4(w23, xb0, xb1, xb2, xb3, 23);
    FMAC4(w24, xb0, xb1, xb2, xb3, 24); FMAC4(w25, xb0, xb1, xb2, xb3, 25);
    FMAC4(w26, xb0, xb1, xb2, xb3, 26); FMAC4(w27, xb0, xb1, xb2, xb3, 27);
    FMAC4(w28, xb0, xb1, xb2, xb3, 28); FMAC4(w29, xb0, xb1, xb2, xb3, 29);
    FMAC4(w30, xb0, xb1, xb2, xb3, 30); FMAC4(w31, xb0, xb1, xb2, xb3, 31);

    const bool is_g = ((tid >> 6) == 2);
    gact[0][tid] = is_g ? ftanh(acc0) : fsigm(acc0);
    gact[1][tid] = is_g ? ftanh(acc1) : fsigm(acc1);
    gact[2][tid] = is_g ? ftanh(acc2) : fsigm(acc2);
    gact[3][tid] = is_g ? ftanh(acc3) : fsigm(acc3);
    __syncthreads();

    {
        const int cb = tid >> 6, cj = tid & 63;
        float ig = gact[cb][cj];
        float gg = gact[cb][2 * HH + cj];
        float og = gact[cb][3 * HH + cj];
        float c = ig * gg;
        float h = og * ftanh(c);
        last[cb][HH + cj] = h;
        last[cb][cj] = g_hf[(size_t)(b0 + cb) * HH + cj];
    }
    __syncthreads();

    if (tid < 8) {
        int b = tid >> 1, o = tid & 1;
        float a = fc_b[o];
#pragma unroll
        for (int j = 0; j < 128; ++j) a += fc_w[o * 128 + j] * last[b][j];
        out[(size_t)(b0 + b) * 2 + o] = a;
    }
}

extern "C" void kernel_launch(void* const* d_in, const int* in_sizes, int n_in,
                              void* d_out, int out_size, void* d_ws, size_t ws_size,
                              hipStream_t stream) {
    const float* x     = (const float*)d_in[0];
    const float* w_ih0 = (const float*)d_in[1];
    const float* w_hh0 = (const float*)d_in[2];
    const float* b_ih0 = (const float*)d_in[3];
    const float* b_hh0 = (const float*)d_in[4];
    const float* w_ih1 = (const float*)d_in[5];
    const float* w_hh1 = (const float*)d_in[6];
    const float* b_ih1 = (const float*)d_in[7];
    const float* b_hh1 = (const float*)d_in[8];
    const float* fc_w  = (const float*)d_in[9];
    const float* fc_b  = (const float*)d_in[10];
    float* out = (float*)d_out;

    pre_gemm0<<<2048, 256, 0, stream>>>(x, w_ih0, b_ih0, b_hh0);
    lstm_scan<0><<<512, 256, 0, stream>>>(w_hh0);
    pre_gemm1<<<2048, 256, 0, stream>>>(w_ih1, b_ih1, b_hh1);
    lstm_scan<1><<<256, 256, 0, stream>>>(w_hh1);
    lstm_final<<<256, 256, 0, stream>>>(w_ih1, b_ih1, b_hh1, fc_w, fc_b, out);
}

// Round 2
// 2623.222 us; speedup vs baseline: 1.5109x; 1.5109x over previous
//
#include <hip/hip_runtime.h>

#define TT 512
#define BB 1024
#define FF 32
#define HH 64
#define GG 256   // 4*H gates per direction

// Static device scratch (ws_size-independent). Fully overwritten every call.
__device__ float g_h1[(size_t)TT * BB * 2 * HH];   // [T][B][128] layer-1 input
__device__ float g_pre0[(size_t)2 * TT * BB * GG]; // [dir][T][B][256] layer-0 pre-gates
__device__ float g_pre1[(size_t)TT * BB * GG];     // [T][B][256] layer-1 fwd pre-gates
__device__ float g_hf[(size_t)BB * HH];            // [B][64] final fwd h of layer1

__device__ __forceinline__ float fsigm(float x) {
    float e = __builtin_amdgcn_exp2f(x * -1.44269504088896f);
    return __builtin_amdgcn_rcpf(1.0f + e);
}
__device__ __forceinline__ float ftanh(float x) {
    float e = __builtin_amdgcn_exp2f(x * -2.88539008177793f);
    return 2.0f * __builtin_amdgcn_rcpf(1.0f + e) - 1.0f;
}
// Wave-uniform broadcast via v_readlane (VALU, zero LDS-pipe cost).
__device__ __forceinline__ float rlane(float v, int l) {
    return __int_as_float(__builtin_amdgcn_readlane(__float_as_int(v), l));
}

// ---------------------------------------------------------------------------
// Layer-0 input pre-gates (unchanged).
// ---------------------------------------------------------------------------
__global__ __launch_bounds__(256, 4) void pre_gemm0(
    const float* __restrict__ x,      // [B][T][F]
    const float* __restrict__ w_ih,   // [2][G][F]
    const float* __restrict__ b_ih,
    const float* __restrict__ b_hh)
{
    const int tid = threadIdx.x;          // gate
    const int b   = blockIdx.x >> 1;
    const int dir = blockIdx.x & 1;

    __shared__ __align__(16) float4 w4[8 * 256];    // [kq][gate], 32 KB
    __shared__ __align__(16) float xbuf[2][256];    // 8 t-rows x 32 f, dbuf

    const float4* wsrc = (const float4*)(w_ih + ((size_t)dir * GG + tid) * FF);
#pragma unroll
    for (int kq = 0; kq < 8; ++kq) w4[kq * 256 + tid] = wsrc[kq];
    const float bias = b_ih[dir * GG + tid] + b_hh[dir * GG + tid];

    const float* xbase = x + (size_t)b * TT * FF;
    xbuf[0][tid] = xbase[tid];            // tile 0 (rows 0..7), coalesced
    const size_t OS = (size_t)BB * GG;

    for (int tc = 0; tc < 64; ++tc) {
        const int cur = tc & 1;
        __syncthreads();   // xbuf[cur] ready; prev reads of xbuf[1-cur] done

        float vnext = 0.f;
        if (tc + 1 < 64) vnext = xbase[(tc + 1) * 256 + tid];   // coalesced

        float a0 = bias, a1 = bias, a2 = bias, a3 = bias,
              a4 = bias, a5 = bias, a6 = bias, a7 = bias;
#pragma unroll
        for (int kq = 0; kq < 8; ++kq) {
            float4 wq = w4[kq * 256 + tid];
            const float4* xr = (const float4*)xbuf[cur];
            float4 q;
            q = xr[0 * 8 + kq]; a0 += q.x*wq.x + q.y*wq.y + q.z*wq.z + q.w*wq.w;
            q = xr[1 * 8 + kq]; a1 += q.x*wq.x + q.y*wq.y + q.z*wq.z + q.w*wq.w;
            q = xr[2 * 8 + kq]; a2 += q.x*wq.x + q.y*wq.y + q.z*wq.z + q.w*wq.w;
            q = xr[3 * 8 + kq]; a3 += q.x*wq.x + q.y*wq.y + q.z*wq.z + q.w*wq.w;
            q = xr[4 * 8 + kq]; a4 += q.x*wq.x + q.y*wq.y + q.z*wq.z + q.w*wq.w;
            q = xr[5 * 8 + kq]; a5 += q.x*wq.x + q.y*wq.y + q.z*wq.z + q.w*wq.w;
            q = xr[6 * 8 + kq]; a6 += q.x*wq.x + q.y*wq.y + q.z*wq.z + q.w*wq.w;
            q = xr[7 * 8 + kq]; a7 += q.x*wq.x + q.y*wq.y + q.z*wq.z + q.w*wq.w;
        }
        float* op = g_pre0 + (((size_t)dir * TT + tc * 8) * BB + b) * GG + tid;
        op[0] = a0; op[1 * OS] = a1; op[2 * OS] = a2; op[3 * OS] = a3;
        op[4 * OS] = a4; op[5 * OS] = a5; op[6 * OS] = a6; op[7 * OS] = a7;

        if (tc + 1 < 64) xbuf[1 - cur][tid] = vnext;
    }
}

// ---------------------------------------------------------------------------
// Wave-per-(batch,dir) recurrent scan, v3. ONE wave per block
// (__launch_bounds__(64,1) -> 512-VGPR cap) so ALL FOUR gate weight rows
// live in VGPRs (64 float4 = 256 VGPR): no LDS, no barriers, no spill.
// Lane l owns cell l and gates {l, 64+l, 128+l, 192+l}; h broadcast is one
// v_readlane feeding 4 FMAs. Pre-gate stream prefetched 2 steps deep
// (~1400 cyc in flight > 900 cyc HBM latency) to cover 1-wave/SIMD occupancy.
// L=0: layer0 both dirs (grid 2048). L=1: layer1 fwd (grid 1024).
// ---------------------------------------------------------------------------
template <int L>
__global__ __launch_bounds__(64, 1) void lstm_scan(
    const float* __restrict__ w_hh)   // [2][G][64]
{
    const int l   = threadIdx.x;
    const int dir = (L == 0) ? (blockIdx.x & 1) : 0;
    const int b   = (L == 0) ? (int)(blockIdx.x >> 1) : (int)blockIdx.x;

    const float* wbase = w_hh + (size_t)dir * GG * HH;

    // Per-lane register weight rows: i(l), f(64+l), g(128+l), o(192+l).
    float4 wi[16], wf[16], wg[16], wo[16];
    {
        const float4* pi_ = (const float4*)(wbase + (size_t)(0   + l) * HH);
        const float4* pf_ = (const float4*)(wbase + (size_t)(64  + l) * HH);
        const float4* pg_ = (const float4*)(wbase + (size_t)(128 + l) * HH);
        const float4* po_ = (const float4*)(wbase + (size_t)(192 + l) * HH);
#pragma unroll
        for (int q = 0; q < 16; ++q) {
            wi[q] = pi_[q]; wf[q] = pf_[q]; wg[q] = pg_[q]; wo[q] = po_[q];
        }
    }

    const float* pre = (L == 0) ? (g_pre0 + (size_t)dir * TT * BB * GG) : g_pre1;

    float c = 0.f, h = 0.f;

    // 2-deep pre-gate prefetch pipeline (explicit register rotation — no
    // runtime-indexed arrays, rule #20).
    const int t0 = dir ? (TT - 1) : 0;
    const int t1 = dir ? (TT - 2) : 1;
    const float* pp0 = pre + ((size_t)t0 * BB + b) * GG;
    const float* pp1 = pre + ((size_t)t1 * BB + b) * GG;
    float ci0 = pp0[l], cf0 = pp0[64 + l], cg0 = pp0[128 + l], co0 = pp0[192 + l];
    float ci1 = pp1[l], cf1 = pp1[64 + l], cg1 = pp1[128 + l], co1 = pp1[192 + l];

    for (int s = 0; s < TT; ++s) {
        const int t = dir ? (TT - 1 - s) : s;

        // Issue prefetch for step s+2 (consumed two iterations from now).
        float ni = 0.f, nf = 0.f, ng = 0.f, no_ = 0.f;
        if (s + 2 < TT) {
            const int tn = dir ? (TT - 3 - s) : (s + 2);
            const float* np = pre + ((size_t)tn * BB + b) * GG;
            ni = np[l]; nf = np[64 + l]; ng = np[128 + l]; no_ = np[192 + l];
        }

        float ai = ci0, af = cf0, ag = cg0, ao = co0;

#define STEPQ(q) do {                                                        \
        float s0 = rlane(h, 4*(q)+0), s1 = rlane(h, 4*(q)+1),                \
              s2 = rlane(h, 4*(q)+2), s3 = rlane(h, 4*(q)+3);                \
        ai += s0*wi[q].x + s1*wi[q].y + s2*wi[q].z + s3*wi[q].w;             \
        af += s0*wf[q].x + s1*wf[q].y + s2*wf[q].z + s3*wf[q].w;             \
        ag += s0*wg[q].x + s1*wg[q].y + s2*wg[q].z + s3*wg[q].w;             \
        ao += s0*wo[q].x + s1*wo[q].y + s2*wo[q].z + s3*wo[q].w;             \
    } while (0)

        STEPQ(0);  STEPQ(1);  STEPQ(2);  STEPQ(3);
        STEPQ(4);  STEPQ(5);  STEPQ(6);  STEPQ(7);
        STEPQ(8);  STEPQ(9);  STEPQ(10); STEPQ(11);
        STEPQ(12); STEPQ(13); STEPQ(14); STEPQ(15);
#undef STEPQ

        const float ig = fsigm(ai);
        const float fg = fsigm(af);
        const float gg = ftanh(ag);
        const float og = fsigm(ao);
        c = fg * c + ig * gg;
        h = og * ftanh(c);

        if (L == 0) {
            g_h1[((size_t)t * BB + b) * (2 * HH) + dir * HH + l] = h;  // coalesced 256B
        } else {
            if (s == TT - 1) g_hf[(size_t)b * HH + l] = h;
        }

        // Rotate the prefetch pipeline.
        ci0 = ci1; cf0 = cf1; cg0 = cg1; co0 = co1;
        ci1 = ni;  cf1 = nf;  cg1 = ng;  co1 = no_;
    }
}

// ---------------------------------------------------------------------------
// Layer-1 forward input pre-gates (unchanged).
// ---------------------------------------------------------------------------
__global__ __launch_bounds__(256, 2) void pre_gemm1(
    const float* __restrict__ w_ih,   // [2][G][128] (dir 0 used)
    const float* __restrict__ b_ih,
    const float* __restrict__ b_hh)
{
    const int tid  = threadIdx.x;
    const int gl   = tid & 127;
    const int rg   = tid >> 7;
    const int b    = blockIdx.x >> 1;
    const int gate = (blockIdx.x & 1) * 128 + gl;

    __shared__ __align__(16) float4 w4[28 * 128];       // quads 0..27, 56 KB
    __shared__ __align__(16) float4 hstg[2][8 * 32];    // 8 t-rows x 32 q, dbuf 8 KB

    const float4* wsrc = (const float4*)w_ih + (size_t)gate * 32;
#pragma unroll
    for (int i = 0; i < 14; ++i) {
        int kq = rg * 14 + i;
        w4[kq * 128 + gl] = wsrc[kq];
    }
    float4 wr0 = wsrc[28], wr1 = wsrc[29], wr2 = wsrc[30], wr3 = wsrc[31];
    const float bias = b_ih[gate] + b_hh[gate];

    const int srow = tid >> 5, sq = tid & 31;
    hstg[0][srow * 32 + sq] =
        *((const float4*)(g_h1 + ((size_t)srow * BB + b) * 128) + sq);

    const size_t RS = (size_t)BB * GG;    // pre1 t-stride (floats)

    for (int tc = 0; tc < 64; ++tc) {
        const int cur = tc & 1;
        __syncthreads();   // hstg[cur] + w4 ready

        float4 vnext = make_float4(0.f, 0.f, 0.f, 0.f);
        if (tc + 1 < 64)
            vnext = *((const float4*)(g_h1 +
                      ((size_t)((tc + 1) * 8 + srow) * BB + b) * 128) + sq);

        const float4* hr0 = &hstg[cur][(rg * 4 + 0) * 32];
        const float4* hr1 = &hstg[cur][(rg * 4 + 1) * 32];
        const float4* hr2 = &hstg[cur][(rg * 4 + 2) * 32];
        const float4* hr3 = &hstg[cur][(rg * 4 + 3) * 32];

        float a0 = bias, a1 = bias, a2 = bias, a3 = bias;
#pragma unroll
        for (int kq = 0; kq < 28; ++kq) {
            float4 wq = w4[kq * 128 + gl];
            float4 q;
            q = hr0[kq]; a0 += q.x*wq.x + q.y*wq.y + q.z*wq.z + q.w*wq.w;
            q = hr1[kq]; a1 += q.x*wq.x + q.y*wq.y + q.z*wq.z + q.w*wq.w;
            q = hr2[kq]; a2 += q.x*wq.x + q.y*wq.y + q.z*wq.z + q.w*wq.w;
            q = hr3[kq]; a3 += q.x*wq.x + q.y*wq.y + q.z*wq.z + q.w*wq.w;
        }
        {
            float4 q;
            q = hr0[28]; a0 += q.x*wr0.x + q.y*wr0.y + q.z*wr0.z + q.w*wr0.w;
            q = hr1[28]; a1 += q.x*wr0.x + q.y*wr0.y + q.z*wr0.z + q.w*wr0.w;
            q = hr2[28]; a2 += q.x*wr0.x + q.y*wr0.y + q.z*wr0.z + q.w*wr0.w;
            q = hr3[28]; a3 += q.x*wr0.x + q.y*wr0.y + q.z*wr0.z + q.w*wr0.w;
            q = hr0[29]; a0 += q.x*wr1.x + q.y*wr1.y + q.z*wr1.z + q.w*wr1.w;
            q = hr1[29]; a1 += q.x*wr1.x + q.y*wr1.y + q.z*wr1.z + q.w*wr1.w;
            q = hr2[29]; a2 += q.x*wr1.x + q.y*wr1.y + q.z*wr1.z + q.w*wr1.w;
            q = hr3[29]; a3 += q.x*wr1.x + q.y*wr1.y + q.z*wr1.z + q.w*wr1.w;
            q = hr0[30]; a0 += q.x*wr2.x + q.y*wr2.y + q.z*wr2.z + q.w*wr2.w;
            q = hr1[30]; a1 += q.x*wr2.x + q.y*wr2.y + q.z*wr2.z + q.w*wr2.w;
            q = hr2[30]; a2 += q.x*wr2.x + q.y*wr2.y + q.z*wr2.z + q.w*wr2.w;
            q = hr3[30]; a3 += q.x*wr2.x + q.y*wr2.y + q.z*wr2.z + q.w*wr2.w;
            q = hr0[31]; a0 += q.x*wr3.x + q.y*wr3.y + q.z*wr3.z + q.w*wr3.w;
            q = hr1[31]; a1 += q.x*wr3.x + q.y*wr3.y + q.z*wr3.z + q.w*wr3.w;
            q = hr2[31]; a2 += q.x*wr3.x + q.y*wr3.y + q.z*wr3.z + q.w*wr3.w;
            q = hr3[31]; a3 += q.x*wr3.x + q.y*wr3.y + q.z*wr3.z + q.w*wr3.w;
        }
        {
            const int tb = tc * 8 + rg * 4;
            float* op = g_pre1 + ((size_t)tb * BB + b) * GG + gate;
            op[0 * RS] = a0; op[1 * RS] = a1; op[2 * RS] = a2; op[3 * RS] = a3;
        }
        if (tc + 1 < 64) hstg[1 - cur][srow * 32 + sq] = vnext;
    }
}

// ---------------------------------------------------------------------------
// Layer 1 backward single step (zero state on h1[T-1]) + FC head (unchanged).
// ---------------------------------------------------------------------------
#define FMAC4(W, P0, P1, P2, P3, K) do{                                   \
    float4 v_;                                                           \
    v_ = (P0)[K]; acc0 += W.x*v_.x; acc0 += W.y*v_.y; acc0 += W.z*v_.z; acc0 += W.w*v_.w; \
    v_ = (P1)[K]; acc1 += W.x*v_.x; acc1 += W.y*v_.y; acc1 += W.z*v_.z; acc1 += W.w*v_.w; \
    v_ = (P2)[K]; acc2 += W.x*v_.x; acc2 += W.y*v_.y; acc2 += W.z*v_.z; acc2 += W.w*v_.w; \
    v_ = (P3)[K]; acc3 += W.x*v_.x; acc3 += W.y*v_.y; acc3 += W.z*v_.z; acc3 += W.w*v_.w; \
}while(0)

__global__ __launch_bounds__(256, 2) void lstm_final(
    const float* __restrict__ w_ih,   // [2][G][128] (dir 1)
    const float* __restrict__ b_ih,
    const float* __restrict__ b_hh,
    const float* __restrict__ fc_w,   // [2][128]
    const float* __restrict__ fc_b,   // [2]
    float* __restrict__ out)          // [B][2]
{
    const int tid = threadIdx.x;
    const int b0  = blockIdx.x * 4;

    __shared__ __align__(16) float x_lds[4][128];
    __shared__ __align__(16) float gact[4][GG];
    __shared__ __align__(16) float last[4][128];

#pragma unroll
    for (int r = 0; r < 2; ++r) {
        int idx = tid + r * 256;
        int b = idx >> 7, col = idx & 127;
        x_lds[b][col] = g_h1[((size_t)(TT - 1) * BB + (b0 + b)) * 128 + col];
    }

    const float4* p = (const float4*)(w_ih + ((size_t)GG + tid) * 128);
    float4 w0 = p[0],  w1 = p[1],  w2 = p[2],  w3 = p[3],  w4 = p[4],  w5 = p[5],
           w6 = p[6],  w7 = p[7],  w8 = p[8],  w9 = p[9],  w10 = p[10], w11 = p[11],
           w12 = p[12], w13 = p[13], w14 = p[14], w15 = p[15], w16 = p[16], w17 = p[17],
           w18 = p[18], w19 = p[19], w20 = p[20], w21 = p[21], w22 = p[22], w23 = p[23],
           w24 = p[24], w25 = p[25], w26 = p[26], w27 = p[27], w28 = p[28], w29 = p[29],
           w30 = p[30], w31 = p[31];
    const float bias = b_ih[GG + tid] + b_hh[GG + tid];
    __syncthreads();

    const float4* xb0 = (const float4*)x_lds[0];
    const float4* xb1 = (const float4*)x_lds[1];
    const float4* xb2 = (const float4*)x_lds[2];
    const float4* xb3 = (const float4*)x_lds[3];

    float acc0 = bias, acc1 = bias, acc2 = bias, acc3 = bias;
    FMAC4(w0, xb0, xb1, xb2, xb3, 0);   FMAC4(w1, xb0, xb1, xb2, xb3, 1);
    FMAC4(w2, xb0, xb1, xb2, xb3, 2);   FMAC4(w3, xb0, xb1, xb2, xb3, 3);
    FMAC4(w4, xb0, xb1, xb2, xb3, 4);   FMAC4(w5, xb0, xb1, xb2, xb3, 5);
    FMAC4(w6, xb0, xb1, xb2, xb3, 6);   FMAC4(w7, xb0, xb1, xb2, xb3, 7);
    FMAC4(w8, xb0, xb1, xb2, xb3, 8);   FMAC4(w9, xb0, xb1, xb2, xb3, 9);
    FMAC4(w10, xb0, xb1, xb2, xb3, 10); FMAC4(w11, xb0, xb1, xb2, xb3, 11);
    FMAC4(w12, xb0, xb1, xb2, xb3, 12); FMAC4(w13, xb0, xb1, xb2, xb3, 13);
    FMAC4(w14, xb0, xb1, xb2, xb3, 14); FMAC4(w15, xb0, xb1, xb2, xb3, 15);
    FMAC4(w16, xb0, xb1, xb2, xb3, 16); FMAC4(w17, xb0, xb1, xb2, xb3, 17);
    FMAC4(w18, xb0, xb1, xb2, xb3, 18); FMAC4(w19, xb0, xb1, xb2, xb3, 19);
    FMAC4(w20, xb0, xb1, xb2, xb3, 20); FMAC4(w21, xb0, xb1, xb2, xb3, 21);
    FMAC4(w22, xb0, xb1, xb2, xb3, 22); FMAC4(w23, xb0, xb1, xb2, xb3, 23);
    FMAC4(w24, xb0, xb1, xb2, xb3, 24); FMAC4(w25, xb0, xb1, xb2, xb3, 25);
    FMAC4(w26, xb0, xb1, xb2, xb3, 26); FMAC4(w27, xb0, xb1, xb2, xb3, 27);
    FMAC4(w28, xb0, xb1, xb2, xb3, 28); FMAC4(w29, xb0, xb1, xb2, xb3, 29);
    FMAC4(w30, xb0, xb1, xb2, xb3, 30); FMAC4(w31, xb0, xb1, xb2, xb3, 31);

    const bool is_g = ((tid >> 6) == 2);
    gact[0][tid] = is_g ? ftanh(acc0) : fsigm(acc0);
    gact[1][tid] = is_g ? ftanh(acc1) : fsigm(acc1);
    gact[2][tid] = is_g ? ftanh(acc2) : fsigm(acc2);
    gact[3][tid] = is_g ? ftanh(acc3) : fsigm(acc3);
    __syncthreads();

    {
        const int cb = tid >> 6, cj = tid & 63;
        float ig = gact[cb][cj];
        float gg = gact[cb][2 * HH + cj];
        float og = gact[cb][3 * HH + cj];
        float c = ig * gg;
        float h = og * ftanh(c);
        last[cb][HH + cj] = h;
        last[cb][cj] = g_hf[(size_t)(b0 + cb) * HH + cj];
    }
    __syncthreads();

    if (tid < 8) {
        int b = tid >> 1, o = tid & 1;
        float a = fc_b[o];
#pragma unroll
        for (int j = 0; j < 128; ++j) a += fc_w[o * 128 + j] * last[b][j];
        out[(size_t)(b0 + b) * 2 + o] = a;
    }
}

extern "C" void kernel_launch(void* const* d_in, const int* in_sizes, int n_in,
                              void* d_out, int out_size, void* d_ws, size_t ws_size,
                              hipStream_t stream) {
    const float* x     = (const float*)d_in[0];
    const float* w_ih0 = (const float*)d_in[1];
    const float* w_hh0 = (const float*)d_in[2];
    const float* b_ih0 = (const float*)d_in[3];
    const float* b_hh0 = (const float*)d_in[4];
    const float* w_ih1 = (const float*)d_in[5];
    const float* w_hh1 = (const float*)d_in[6];
    const float* b_ih1 = (const float*)d_in[7];
    const float* b_hh1 = (const float*)d_in[8];
    const float* fc_w  = (const float*)d_in[9];
    const float* fc_b  = (const float*)d_in[10];
    float* out = (float*)d_out;

    pre_gemm0<<<2048, 256, 0, stream>>>(x, w_ih0, b_ih0, b_hh0);
    lstm_scan<0><<<2048, 64, 0, stream>>>(w_hh0);
    pre_gemm1<<<2048, 256, 0, stream>>>(w_ih1, b_ih1, b_hh1);
    lstm_scan<1><<<1024, 64, 0, stream>>>(w_hh1);
    lstm_final<<<256, 256, 0, stream>>>(w_ih1, b_ih1, b_hh1, fc_w, fc_b, out);
}